// Round 3
// baseline (12492.149 us; speedup 1.0000x reference)
//
#include <hip/hip_runtime.h>
#include <stdint.h>

#define B_ 64
#define T_ 512
#define I_ 256
#define H_ 512
#define G0_ 128
#define G1_ 128
#define NTHR_ 512
#define D_ 8   // ring depth (power of 2)

typedef __attribute__((ext_vector_type(8))) short short8;
typedef __attribute__((ext_vector_type(4))) float float4v;
typedef __attribute__((ext_vector_type(4))) unsigned int uint4v;

static_assert(sizeof(short8) == 16, "");
static_assert(sizeof(uint4v) == 16, "");

#define SLOT_STRIDE (B_ * H_)   // u32 per ring slot (plain [b][n] layout)

// ---- bf16 helpers (round-to-nearest-even) ----
__device__ __forceinline__ unsigned short f2bf(float x) {
  union { float f; uint32_t u; } v; v.f = x;
  uint32_t r = v.u + 0x7FFFu + ((v.u >> 16) & 1u);
  return (unsigned short)(r >> 16);
}
__device__ __forceinline__ float bf2f(unsigned short h) {
  union { uint32_t u; float f; } v; v.u = ((uint32_t)h) << 16; return v.f;
}
__device__ __forceinline__ void splitHL(float x, unsigned short& hi, unsigned short& lo) {
  hi = f2bf(x);
  lo = f2bf(x - bf2f(hi));   // x - hi is exact in fp32
}

// per-thread spin on a single progress word (cache-bypass load, no fences)
__device__ __forceinline__ void wait_ge(const uint32_t* p, int tgt) {
  if (tgt <= 0) return;
  int it = 0;
  while ((int)__hip_atomic_load(p, __ATOMIC_RELAXED, __HIP_MEMORY_SCOPE_AGENT) < tgt) {
    if (++it > 2000000) break;   // safety: degrade to wrong answer, never hang
  }
}

__device__ __forceinline__ void unpack8(uint4v w0, uint4v w1, short8& hi, short8& lo) {
  #pragma unroll
  for (int j = 0; j < 4; ++j) {
    hi[j]     = (short)(w0[j] >> 16); lo[j]     = (short)(w0[j] & 0xffffu);
    hi[j + 4] = (short)(w1[j] >> 16); lo[j + 4] = (short)(w1[j] & 0xffffu);
  }
}

#define MFMA16(A, Bv, C) __builtin_amdgcn_mfma_f32_16x16x32_bf16(A, Bv, C, 0, 0, 0)

// One LSTM layer, persistent across all T steps.
// Block 'a' owns h-columns [4a, 4a+4) -> 16 gate columns (4 gates x 4 cols).
// K space: [0,K1)=inp (x or h0), [K1,K1+512)=h_rec.
// MFMA frag conventions:
//   k(q,j) = 4q + (j&3) + 16*(j>>2), q = lane>>4
//   A: row m = lane&15, B: col = lane&15
//   C/D: col = lane&15, row = 4*(lane>>4) + i   (m89-verified)
// Ring protocol: writer sc0/sc1 write-through stores -> vmcnt(0) -> barrier ->
// flag (bypass store). Reader: poll flag (bypass load) -> buffer_inv sc1
// (drop stale clean L2 lines; NO wbl2) -> plain cached dwordx4 loads (pipelined
// by compiler, L2-shared across the XCD's 32 blocks).
template <int LAYER>
__device__ void run_layer(
    int a,
    const float* __restrict__ x,
    const float* __restrict__ Wxp, const float* __restrict__ bxp,
    const float* __restrict__ Whp,
    uint32_t* prog0, uint32_t* prog1,
    uint32_t* ring0, uint32_t* ring1,
    float* h1f,
    unsigned short* Wsh, float* red)
{
  constexpr int K1 = LAYER ? H_ : I_;
  constexpr int NT = (K1 + H_) / 32;   // 24 (L0) or 32 (L1) K-tiles
  constexpr int NTT = NT / 2;          // tiles per k-half wavegroup
  const int tid = threadIdx.x;
  const int lane = tid & 63;
  const int wid = tid >> 6;     // 0..7
  const int bg = wid & 3;       // batch group (16 batches)
  const int kh = wid >> 2;      // K-half (parity of tile)
  const int qq = lane >> 4;
  const int cc = lane & 15;     // A-row / gate column within block
  const int brow = bg * 16 + cc;

  // ---- stage weight slice: pass0 = LO (pulled to regs), pass1 = HI (stays in LDS) ----
  short8 wlo[NTT];
  for (int pass = 0; pass < 2; ++pass) {
    for (int idx = tid; idx < NT * 512; idx += NTHR_) {
      int tile = idx >> 9, r = idx & 511, ln = r >> 3, j = r & 7;
      int k = tile * 32 + 4 * (ln >> 4) + (j & 3) + 16 * (j >> 2);
      int n = 4 * a + (ln & 3);
      int g = (ln & 15) >> 2;
      float wvv = (k < K1) ? Wxp[((size_t)g * K1 + k) * H_ + n]
                           : Whp[((size_t)g * H_ + (k - K1)) * H_ + n];
      unsigned short hi, lo; splitHL(wvv, hi, lo);
      Wsh[idx] = pass ? hi : lo;
    }
    __syncthreads();
    if (pass == 0) {
      #pragma unroll
      for (int tt = 0; tt < NTT; ++tt) {
        int tile = 2 * tt + kh;
        wlo[tt] = *(const short8*)(Wsh + tile * 512 + lane * 8);
      }
      __syncthreads();   // all pulled before HI overwrites
    }
  }

  const float biasv = bxp[(size_t)(cc >> 2) * H_ + 4 * a + (cc & 3)];
  float cst[4] = {0.f, 0.f, 0.f, 0.f};

  uint32_t* myprog = LAYER ? prog1 : prog0;

  for (int t = 0; t < T_; ++t) {
    // ---- wait: read-ready + ring backpressure, per-block flags, zero contention ----
    // L0@t: prog0[*]>=t (h0[t-1] ready), prog1[*]>=t-7 (L1 consumed h0[t-8])
    // L1@t: prog0[*]>=t+1 (h0[t] ready), prog1[*]>=t (h1[t-1] ready)
    const int tgt0 = LAYER ? (t + 1) : t;
    const int tgt1 = LAYER ? t : (t - (D_ - 1));
    if (tid < 128)      wait_ge(&prog0[tid], tgt0);
    else if (tid < 256) wait_ge(&prog1[tid - 128], tgt1);
    __syncthreads();
    // acquire: invalidate stale clean lines in this XCD's L2/L1. Data is in the
    // MALL (writer used write-through + drained before flag), so post-inv
    // fetches are correct and get L2-cached for the whole XCD.
    asm volatile("buffer_inv sc1" ::: "memory");

    const int sp = (t - 1) & (D_ - 1);
    const int sc = t & (D_ - 1);
    float bv = (kh == 0) ? biasv : 0.f;
    float4v acc = {bv, bv, bv, bv};

    #pragma unroll
    for (int tt = 0; tt < NTT; ++tt) {
      const int tile = 2 * tt + kh;
      short8 ahi, alo;
      if (!LAYER && tt < 4) {
        // x fragment built on the fly from fp32 (read-only: cached loads)
        const float* xp = x + ((size_t)brow * T_ + t) * I_ + tile * 32 + 4 * qq;
        float4v f0 = *(const float4v*)xp;
        float4v f1 = *(const float4v*)(xp + 16);
        #pragma unroll
        for (int j = 0; j < 4; ++j) {
          unsigned short hh, ll;
          splitHL(f0[j], hh, ll); ahi[j] = (short)hh; alo[j] = (short)ll;
          splitHL(f1[j], hh, ll); ahi[j + 4] = (short)hh; alo[j + 4] = (short)ll;
        }
      } else {
        const uint32_t* p;
        if (!LAYER)      p = ring0 + (size_t)sp * SLOT_STRIDE + (size_t)brow * H_ + (tile * 32 - I_) + 4 * qq;
        else if (tt < 8) p = ring0 + (size_t)sc * SLOT_STRIDE + (size_t)brow * H_ + tile * 32 + 4 * qq;
        else             p = ring1 + (size_t)sp * SLOT_STRIDE + (size_t)brow * H_ + (tile * 32 - H_) + 4 * qq;
        uint4v w0 = *(const uint4v*)p;
        uint4v w1 = *(const uint4v*)(p + 16);
        unpack8(w0, w1, ahi, alo);
      }
      short8 bhi = *(const short8*)(Wsh + tile * 512 + lane * 8);
      acc = MFMA16(ahi, bhi, acc);       // hi*hi
      acc = MFMA16(alo, bhi, acc);       // lo*hi
      acc = MFMA16(ahi, wlo[tt], acc);   // hi*lo
    }

    // ---- split-K reduction through LDS ----
    if (kh == 1) *(float4v*)(red + ((bg << 6) + lane) * 4) = acc;
    __syncthreads();
    if (kh == 0) {
      acc += *(const float4v*)(red + ((bg << 6) + lane) * 4);

      // activations: cols 0-11 sigmoid (i,f,o), 12-15 tanh (g)
      const bool isg = cc >= 12;
      float av[4];
      #pragma unroll
      for (int i = 0; i < 4; ++i) {
        float xg = acc[i];
        float arg = isg ? xg + xg : xg;
        float e = __expf(-fabsf(arg));
        float s = (arg >= 0.f) ? 1.f / (1.f + e) : e / (1.f + e);
        av[i] = isg ? (s + s - 1.f) : s;   // tanh(x) = 2*sigmoid(2x)-1
      }
      float hn[4];
      #pragma unroll
      for (int i = 0; i < 4; ++i) {
        float fv = __shfl_xor(av[i], 4);
        float ov = __shfl_xor(av[i], 8);
        float gv = __shfl_xor(av[i], 12);
        float cn = fv * cst[i] + av[i] * gv;
        cst[i] = cn;
        float e2 = __expf(-2.f * fabsf(cn));
        float th = (1.f - e2) / (1.f + e2);
        hn[i] = ov * ((cn >= 0.f) ? th : -th);
      }
      // in-wave transpose: lane (qq, cc<4) gathers row 4qq+cc, cols 4a+0..3
      float v0[4], v1[4], v2[4], v3[4];
      #pragma unroll
      for (int d = 0; d < 4; ++d) {
        int src = (lane & 0x30) | d;
        v0[d] = __shfl(hn[0], src);
        v1[d] = __shfl(hn[1], src);
        v2[d] = __shfl(hn[2], src);
        v3[d] = __shfl(hn[3], src);
      }
      if (cc < 4) {
        uint4v pk; float4v hf;
        #pragma unroll
        for (int d = 0; d < 4; ++d) {
          float hv = (cc == 0) ? v0[d] : (cc == 1) ? v1[d] : (cc == 2) ? v2[d] : v3[d];
          hf[d] = hv;
          unsigned short hh, ll; splitHL(hv, hh, ll);
          pk[d] = ((uint32_t)hh << 16) | (uint32_t)ll;
        }
        uint32_t* dst = (LAYER ? ring1 : ring0) + (size_t)sc * SLOT_STRIDE
                        + (size_t)(bg * 16 + 4 * qq + cc) * H_ + 4 * a;
        // write-through to MALL (coherent for cross-XCD readers)
        asm volatile("global_store_dwordx4 %0, %1, off sc0 sc1"
                     :: "v"(dst), "v"(pk) : "memory");
        if (LAYER && t == T_ - 1) {
          float4v* hp = (float4v*)(h1f + (size_t)(bg * 16 + 4 * qq + cc) * H_ + 4 * a);
          asm volatile("global_store_dwordx4 %0, %1, off sc0 sc1"
                       :: "v"(hp), "v"(hf) : "memory");
        }
      }
    }
    // drain ring stores (acks = globally visible), then block barrier, then flag
    asm volatile("s_waitcnt vmcnt(0)" ::: "memory");
    __syncthreads();
    if (tid == 0)
      __hip_atomic_store(&myprog[a], (uint32_t)(t + 1),
                         __ATOMIC_RELAXED, __HIP_MEMORY_SCOPE_AGENT);
  }
}

__global__ __launch_bounds__(NTHR_, 2) void lstm_persist(
    const float* __restrict__ x,
    const float* __restrict__ Wx0, const float* __restrict__ bx0, const float* __restrict__ Wh0,
    const float* __restrict__ Wx1, const float* __restrict__ bx1, const float* __restrict__ Wh1,
    uint32_t* prog0, uint32_t* prog1,
    uint32_t* ring0, uint32_t* ring1,
    float* h1f)
{
  __shared__ unsigned short Wsh[16384];  // 32 KB: W-hi frags
  __shared__ float red[1024];            // 4 KB: split-K reduction
  if (blockIdx.x < G0_)
    run_layer<0>(blockIdx.x, x, Wx0, bx0, Wh0, prog0, prog1, ring0, ring1, h1f, Wsh, red);
  else
    run_layer<1>(blockIdx.x - G0_, x, Wx1, bx1, Wh1, prog0, prog1, ring0, ring1, h1f, Wsh, red);
}

__global__ void fc_out(const float* __restrict__ h1f, const float* __restrict__ Wfc,
                       const float* __restrict__ bfc, float* __restrict__ out)
{
  int tid = threadIdx.x;     // 512 threads: 64 batches x 8 partials
  int b = tid >> 3, p = tid & 7;
  float s = 0.f;
  const float* hp = h1f + (size_t)b * H_ + p * 64;
  const float* wp = Wfc + p * 64;
  #pragma unroll 16
  for (int n = 0; n < 64; ++n) s += hp[n] * wp[n];
  s += __shfl_xor(s, 1);
  s += __shfl_xor(s, 2);
  s += __shfl_xor(s, 4);
  if (p == 0) out[b] = s + bfc[0];
}

extern "C" void kernel_launch(void* const* d_in, const int* in_sizes, int n_in,
                              void* d_out, int out_size, void* d_ws, size_t ws_size,
                              hipStream_t stream)
{
  const float* x   = (const float*)d_in[0];
  const float* Wx0 = (const float*)d_in[1];
  const float* bx0 = (const float*)d_in[2];
  const float* Wh0 = (const float*)d_in[3];
  const float* Wx1 = (const float*)d_in[4];
  const float* bx1 = (const float*)d_in[5];
  const float* Wh1 = (const float*)d_in[6];
  const float* Wfc = (const float*)d_in[7];
  const float* bfc = (const float*)d_in[8];

  uint8_t* ws = (uint8_t*)d_ws;
  uint32_t* prog0 = (uint32_t*)ws;                // 128 u32
  uint32_t* prog1 = (uint32_t*)(ws + 2048);       // 128 u32
  const size_t RINGB = (size_t)D_ * SLOT_STRIDE * 4;   // 1 MB per ring (packed u32)
  uint32_t* ring0 = (uint32_t*)(ws + 4096);
  uint32_t* ring1 = (uint32_t*)(ws + 4096 + RINGB);
  float* h1f = (float*)(ws + 4096 + 2 * RINGB);   // 128 KB, fully rewritten each call

  // flags + rings must be zero every call (slot D-1 is the t=-1 state)
  (void)hipMemsetAsync(ws, 0, 4096 + 2 * RINGB, stream);

  hipLaunchKernelGGL(lstm_persist, dim3(G0_ + G1_), dim3(NTHR_), 0, stream,
                     x, Wx0, bx0, Wh0, Wx1, bx1, Wh1,
                     prog0, prog1, ring0, ring1, h1f);
  hipLaunchKernelGGL(fc_out, dim3(1), dim3(512), 0, stream,
                     h1f, Wfc, bfc, (float*)d_out);
}

// Round 5
// 5352.120 us; speedup vs baseline: 2.3341x; 2.3341x over previous
//
#include <hip/hip_runtime.h>
#include <stdint.h>

#define B_ 64
#define T_ 512
#define I_ 256
#define H_ 512
#define G0_ 128
#define G1_ 128
#define NTHR_ 512
#define D_ 8   // ring depth (power of 2)

typedef __attribute__((ext_vector_type(8))) short short8;
typedef __attribute__((ext_vector_type(4))) float float4v;
typedef __attribute__((ext_vector_type(4))) unsigned int uint4v;

static_assert(sizeof(short8) == 16, "");
static_assert(sizeof(uint4v) == 16, "");

// ---- bf16 helpers (round-to-nearest-even) ----
__device__ __forceinline__ unsigned short f2bf(float x) {
  union { float f; uint32_t u; } v; v.f = x;
  uint32_t r = v.u + 0x7FFFu + ((v.u >> 16) & 1u);
  return (unsigned short)(r >> 16);
}
__device__ __forceinline__ float bf2f(unsigned short h) {
  union { uint32_t u; float f; } v; v.u = ((uint32_t)h) << 16; return v.f;
}
__device__ __forceinline__ void splitHL(float x, unsigned short& hi, unsigned short& lo) {
  hi = f2bf(x);
  lo = f2bf(x - bf2f(hi));   // x - hi is exact in fp32
}

// ring element offset (u32 units). fragment layout: [slot][bg][ktile][lane][j]
// each lane's 8 u32 words are CONTIGUOUS (lane*8): word j at p[j], j=0..7.
__device__ __forceinline__ size_t roff(int slot, int bg, int ht, int lane) {
  return ((size_t)((slot * 4 + bg) * 16 + ht)) * 512 + (size_t)lane * 8;
}

// per-thread spin on a single progress word (bypass load, no fences)
__device__ __forceinline__ void wait_ge(const uint32_t* p, int tgt) {
  if (tgt <= 0) return;
  int it = 0;
  while ((int)__hip_atomic_load(p, __ATOMIC_RELAXED, __HIP_MEMORY_SCOPE_AGENT) < tgt) {
    __builtin_amdgcn_s_sleep(1);
    if (++it > 2000000) break;   // safety: degrade to wrong answer, never hang
  }
}

__device__ __forceinline__ void unpack8(uint4v w0, uint4v w1, short8& hi, short8& lo) {
  #pragma unroll
  for (int j = 0; j < 4; ++j) {
    hi[j]     = (short)(w0[j] >> 16); lo[j]     = (short)(w0[j] & 0xffffu);
    hi[j + 4] = (short)(w1[j] >> 16); lo[j + 4] = (short)(w1[j] & 0xffffu);
  }
}

#define MFMA16(A, Bv, C) __builtin_amdgcn_mfma_f32_16x16x32_bf16(A, Bv, C, 0, 0, 0)

// counted wait on our asm-issued vmem + scheduling fence (rule #18)
#define WAITV(n) do { \
    asm volatile("s_waitcnt vmcnt(" #n ")" ::: "memory"); \
    __builtin_amdgcn_sched_barrier(0); \
  } while (0)

// One LSTM layer, persistent across all T steps.
// Block 'a' owns h-columns [4a, 4a+4) -> 16 gate columns (4 gates x 4 cols).
// K space: [0,K1)=inp (x or h0), [K1,K1+512)=h_rec.
// MFMA frag conventions: k(q,j) = 4q + (j&3) + 16*(j>>2), q = lane>>4
//   A: row m = lane&15, B: col = lane&15
//   C/D: col = lane&15, row = 4*(lane>>4) + i   (m89-verified)
// Ring protocol: writer sc0/sc1 write-through dwordx4 stores -> vmcnt(0) ->
// barrier -> flag (bypass store). Reader: poll flags -> batched inline-asm
// bypass loads (16-32 in flight, counted vmcnt waits). NO cache maintenance.
template <int LAYER>
__device__ void run_layer(
    int a,
    const float* __restrict__ x,
    const float* __restrict__ Wxp, const float* __restrict__ bxp,
    const float* __restrict__ Whp,
    uint32_t* prog0, uint32_t* prog1,
    uint32_t* ring0, uint32_t* ring1,
    float* h1f,
    unsigned short* Wsh, float* red)
{
  constexpr int K1 = LAYER ? H_ : I_;
  constexpr int NT = (K1 + H_) / 32;   // 24 (L0) or 32 (L1) K-tiles
  constexpr int NTT = NT / 2;          // 12 or 16 tiles per k-half wavegroup
  const int tid = threadIdx.x;
  const int lane = tid & 63;
  const int wid = tid >> 6;     // 0..7
  const int bg = wid & 3;       // batch group (16 batches)
  const int kh = wid >> 2;      // K-half (parity of tile)
  const int qq = lane >> 4;
  const int cc = lane & 15;     // A-row / gate column within block
  const int brow = bg * 16 + cc;

  // ---- stage weight slice: pass0 = LO (pulled to regs), pass1 = HI (stays in LDS) ----
  short8 wlo[NTT];
  for (int pass = 0; pass < 2; ++pass) {
    for (int idx = tid; idx < NT * 512; idx += NTHR_) {
      int tile = idx >> 9, r = idx & 511, ln = r >> 3, j = r & 7;
      int k = tile * 32 + 4 * (ln >> 4) + (j & 3) + 16 * (j >> 2);
      int n = 4 * a + (ln & 3);
      int g = (ln & 15) >> 2;
      float wvv = (k < K1) ? Wxp[((size_t)g * K1 + k) * H_ + n]
                           : Whp[((size_t)g * H_ + (k - K1)) * H_ + n];
      unsigned short hi, lo; splitHL(wvv, hi, lo);
      Wsh[idx] = pass ? hi : lo;
    }
    __syncthreads();
    if (pass == 0) {
      #pragma unroll
      for (int tt = 0; tt < NTT; ++tt) {
        int tile = 2 * tt + kh;
        wlo[tt] = *(const short8*)(Wsh + tile * 512 + lane * 8);
      }
      __syncthreads();   // all pulled before HI overwrites
    }
  }

  const float biasv = bxp[(size_t)(cc >> 2) * H_ + 4 * a + (cc & 3)];
  float cst[4] = {0.f, 0.f, 0.f, 0.f};

  uint32_t* myprog = LAYER ? prog1 : prog0;

  for (int t = 0; t < T_; ++t) {
    // ---- wait: read-ready + ring backpressure, per-block flags ----
    // L0@t: prog0[*]>=t (h0[t-1] ready), prog1[*]>=t-7 (slot t&7 free)
    // L1@t: prog0[*]>=t+1 (h0[t] ready), prog1[*]>=t (h1[t-1] ready)
    const int tgt0 = LAYER ? (t + 1) : t;
    const int tgt1 = LAYER ? t : (t - (D_ - 1));
    if (tid < 128)      wait_ge(&prog0[tid], tgt0);
    else if (tid < 256) wait_ge(&prog1[tid - 128], tgt1);
    __syncthreads();

    const int sp = (t - 1) & (D_ - 1);
    const int sc = t & (D_ - 1);
    float bv = (kh == 0) ? biasv : 0.f;
    float4v acc = {bv, bv, bv, bv};

    uint4v w0[NTT], w1[NTT];   // all accesses fully unrolled -> registers

    auto issue_one = [&](int tt) {
      const int tile = 2 * tt + kh;
      if (!LAYER && tt < 4) {
        // x fragment source (read-only input: cached loads). floats: second
        // half of the frag (k+16) is 16 floats = 64 bytes away.
        const float* xp = x + ((size_t)brow * T_ + t) * I_ + tile * 32 + 4 * qq;
        asm volatile("global_load_dwordx4 %0, %2, off\n\t"
                     "global_load_dwordx4 %1, %2, off offset:64"
                     : "=&v"(w0[tt]), "=&v"(w1[tt]) : "v"(xp) : "memory");
      } else {
        const uint32_t* p;
        if (!LAYER)      p = ring0 + roff(sp, bg, tile - 8, lane);
        else if (tt < 8) p = ring0 + roff(sc, bg, tile, lane);
        else             p = ring1 + roff(sp, bg, tile - 16, lane);
        // frag layout: this lane's words 0..7 contiguous -> second dwordx4 at
        // +16 BYTES (words 4..7), NOT +64 (that's lane+2's data).
        asm volatile("global_load_dwordx4 %0, %2, off sc0 sc1\n\t"
                     "global_load_dwordx4 %1, %2, off offset:16 sc0 sc1"
                     : "=&v"(w0[tt]), "=&v"(w1[tt]) : "v"(p) : "memory");
      }
    };

    auto proc_one = [&](int tt) {
      const int tile = 2 * tt + kh;
      short8 ahi, alo;
      if (!LAYER && tt < 4) {
        #pragma unroll
        for (int j = 0; j < 4; ++j) {
          unsigned short hh, ll;
          splitHL(__uint_as_float(w0[tt][j]), hh, ll); ahi[j] = (short)hh; alo[j] = (short)ll;
          splitHL(__uint_as_float(w1[tt][j]), hh, ll); ahi[j + 4] = (short)hh; alo[j + 4] = (short)ll;
        }
      } else {
        unpack8(w0[tt], w1[tt], ahi, alo);
      }
      short8 bhi = *(const short8*)(Wsh + tile * 512 + lane * 8);
      acc = MFMA16(ahi, bhi, acc);       // hi*hi
      acc = MFMA16(alo, bhi, acc);       // lo*hi
      acc = MFMA16(ahi, wlo[tt], acc);   // hi*lo
    };

    // ---- pipelined ring/x reads: batched issue, counted waits ----
    #pragma unroll
    for (int tt = 0; tt < 8; ++tt) issue_one(tt);
    WAITV(8);
    #pragma unroll
    for (int tt = 0; tt < 4; ++tt) proc_one(tt);
    #pragma unroll
    for (int tt = 8; tt < NTT; ++tt) issue_one(tt);
    WAITV(8);
    #pragma unroll
    for (int tt = 4; tt < 8; ++tt) proc_one(tt);
    if constexpr (LAYER) {
      WAITV(8);
      #pragma unroll
      for (int tt = 8; tt < 12; ++tt) proc_one(tt);
      WAITV(0);
      #pragma unroll
      for (int tt = 12; tt < 16; ++tt) proc_one(tt);
    } else {
      WAITV(0);
      #pragma unroll
      for (int tt = 8; tt < 12; ++tt) proc_one(tt);
    }

    // ---- split-K reduction through LDS ----
    if (kh == 1) *(float4v*)(red + ((bg << 6) + lane) * 4) = acc;
    __syncthreads();
    if (kh == 0) {
      acc += *(const float4v*)(red + ((bg << 6) + lane) * 4);

      // activations: cols 0-11 sigmoid (i,f,o), 12-15 tanh (g)
      const bool isg = cc >= 12;
      float av[4];
      #pragma unroll
      for (int i = 0; i < 4; ++i) {
        float xg = acc[i];
        float arg = isg ? xg + xg : xg;
        float e = __expf(-fabsf(arg));
        float s = (arg >= 0.f) ? 1.f / (1.f + e) : e / (1.f + e);
        av[i] = isg ? (s + s - 1.f) : s;   // tanh(x) = 2*sigmoid(2x)-1
      }
      float hn[4];
      #pragma unroll
      for (int i = 0; i < 4; ++i) {
        float fv = __shfl_xor(av[i], 4);
        float ov = __shfl_xor(av[i], 8);
        float gv = __shfl_xor(av[i], 12);
        float cn = fv * cst[i] + av[i] * gv;
        cst[i] = cn;
        float e2 = __expf(-2.f * fabsf(cn));
        float th = (1.f - e2) / (1.f + e2);
        hn[i] = ov * ((cn >= 0.f) ? th : -th);
      }
      // in-wave transpose: lane (qq, cc) gathers row 4qq+cc, cols 4a+0..3
      float v0[4], v1[4], v2[4], v3[4];
      #pragma unroll
      for (int d = 0; d < 4; ++d) {
        int src = (lane & 0x30) | d;
        v0[d] = __shfl(hn[0], src);
        v1[d] = __shfl(hn[1], src);
        v2[d] = __shfl(hn[2], src);
        v3[d] = __shfl(hn[3], src);
      }
      if (cc < 4) {
        uint4v pk; float4v hf;
        #pragma unroll
        for (int d = 0; d < 4; ++d) {
          float hv = (cc == 0) ? v0[d] : (cc == 1) ? v1[d] : (cc == 2) ? v2[d] : v3[d];
          hf[d] = hv;
          unsigned short hh, ll; splitHL(hv, hh, ll);
          pk[d] = ((uint32_t)hh << 16) | (uint32_t)ll;
        }
        // fragment-layout store: lane' = 16*(a&3) + (4qq+cc), words 4*((a>>2)&1)+d
        // -> element (m=4qq+cc, n=4a+d). Verified against roff/k-bijection.
        uint32_t* dst = (LAYER ? ring1 : ring0)
                      + roff(sc, bg, a >> 3, 16 * (a & 3) + 4 * qq + cc)
                      + 4 * ((a >> 2) & 1);
        asm volatile("global_store_dwordx4 %0, %1, off sc0 sc1"
                     :: "v"(dst), "v"(pk) : "memory");
        if (LAYER && t == T_ - 1) {
          float4v* hp = (float4v*)(h1f + (size_t)(bg * 16 + 4 * qq + cc) * H_ + 4 * a);
          asm volatile("global_store_dwordx4 %0, %1, off sc0 sc1"
                       :: "v"(hp), "v"(hf) : "memory");
        }
      }
    }
    // drain ring stores (acked = globally visible), block barrier, publish flag
    asm volatile("s_waitcnt vmcnt(0)" ::: "memory");
    __syncthreads();
    if (tid == 0)
      __hip_atomic_store(&myprog[a], (uint32_t)(t + 1),
                         __ATOMIC_RELAXED, __HIP_MEMORY_SCOPE_AGENT);
  }
}

__global__ __launch_bounds__(NTHR_, 2) void lstm_persist(
    const float* __restrict__ x,
    const float* __restrict__ Wx0, const float* __restrict__ bx0, const float* __restrict__ Wh0,
    const float* __restrict__ Wx1, const float* __restrict__ bx1, const float* __restrict__ Wh1,
    uint32_t* prog0, uint32_t* prog1,
    uint32_t* ring0, uint32_t* ring1,
    float* h1f)
{
  __shared__ unsigned short Wsh[16384];  // 32 KB: W-hi frags
  __shared__ float red[1024];            // 4 KB: split-K reduction
  if (blockIdx.x < G0_)
    run_layer<0>(blockIdx.x, x, Wx0, bx0, Wh0, prog0, prog1, ring0, ring1, h1f, Wsh, red);
  else
    run_layer<1>(blockIdx.x - G0_, x, Wx1, bx1, Wh1, prog0, prog1, ring0, ring1, h1f, Wsh, red);
}

__global__ void fc_out(const float* __restrict__ h1f, const float* __restrict__ Wfc,
                       const float* __restrict__ bfc, float* __restrict__ out)
{
  int tid = threadIdx.x;     // 512 threads: 64 batches x 8 partials
  int b = tid >> 3, p = tid & 7;
  float s = 0.f;
  const float* hp = h1f + (size_t)b * H_ + p * 64;
  const float* wp = Wfc + p * 64;
  #pragma unroll 16
  for (int n = 0; n < 64; ++n) s += hp[n] * wp[n];
  s += __shfl_xor(s, 1);
  s += __shfl_xor(s, 2);
  s += __shfl_xor(s, 4);
  if (p == 0) out[b] = s + bfc[0];
}

extern "C" void kernel_launch(void* const* d_in, const int* in_sizes, int n_in,
                              void* d_out, int out_size, void* d_ws, size_t ws_size,
                              hipStream_t stream)
{
  const float* x   = (const float*)d_in[0];
  const float* Wx0 = (const float*)d_in[1];
  const float* bx0 = (const float*)d_in[2];
  const float* Wh0 = (const float*)d_in[3];
  const float* Wx1 = (const float*)d_in[4];
  const float* bx1 = (const float*)d_in[5];
  const float* Wh1 = (const float*)d_in[6];
  const float* Wfc = (const float*)d_in[7];
  const float* bfc = (const float*)d_in[8];

  uint8_t* ws = (uint8_t*)d_ws;
  uint32_t* prog0 = (uint32_t*)ws;                     // 128 u32
  uint32_t* prog1 = (uint32_t*)(ws + 2048);            // 128 u32
  const size_t RINGB = (size_t)D_ * 4 * 16 * 512 * 4;  // 1 MB per ring (u32 frag layout)
  uint32_t* ring0 = (uint32_t*)(ws + 4096);
  uint32_t* ring1 = (uint32_t*)(ws + 4096 + RINGB);
  float* h1f = (float*)(ws + 4096 + 2 * RINGB);        // 128 KB, fully rewritten each call

  // flags + rings must be zero every call (slot D-1 is the t=-1 state)
  (void)hipMemsetAsync(ws, 0, 4096 + 2 * RINGB, stream);

  hipLaunchKernelGGL(lstm_persist, dim3(G0_ + G1_), dim3(NTHR_), 0, stream,
                     x, Wx0, bx0, Wh0, Wx1, bx1, Wh1,
                     prog0, prog1, ring0, ring1, h1f);
  hipLaunchKernelGGL(fc_out, dim3(1), dim3(512), 0, stream,
                     h1f, Wfc, bfc, (float*)d_out);
}